// Round 9
// baseline (188.463 us; speedup 1.0000x reference)
//
#include <hip/hip_runtime.h>

#define NN 100000
#define NE 1600000
#define DD 128
#define NBLK 98  // ceil(NN / 1024)

typedef __attribute__((ext_vector_type(8))) short bf16x8;
typedef __attribute__((ext_vector_type(4))) float f32x4;
typedef __attribute__((ext_vector_type(2))) float f32x2;

__device__ __forceinline__ float bf2f(unsigned short u) {
    return __uint_as_float(((unsigned)u) << 16);
}
__device__ __forceinline__ unsigned short f2bf(float f) {
    unsigned u = __float_as_uint(f);
    u += 0x7FFFu + ((u >> 16) & 1u);  // round to nearest even
    return (unsigned short)(u >> 16);
}

// ---------------- count, XCD-private copies + per-edge slot ----------------
// deg8[c*8 + xcc] incremented with workgroup-scope atomic -> stays in the
// XCD-local L2 (no sc1 write-through). Copies are XCD-disjoint, so L2-local
// RMW is globally correct. eslot[i] = (xcc<<8) | local_slot.
__global__ void k_count8(const int* __restrict__ col, unsigned* __restrict__ deg8,
                         unsigned* __restrict__ eslot) {
    int i = blockIdx.x * blockDim.x + threadIdx.x;
    // hwreg(HW_REG_XCC_ID=20, offset=0, size=4): imm = (4-1)<<11 | 0<<6 | 20
    unsigned xcc = __builtin_amdgcn_s_getreg(6164) & 7u;
    if (i < NE) {
        int c = col[i];
        unsigned ls = __hip_atomic_fetch_add(&deg8[(size_t)c * 8 + xcc], 1u,
                                             __ATOMIC_RELAXED, __HIP_MEMORY_SCOPE_WORKGROUP);
        eslot[i] = (xcc << 8) | (ls & 255u);
    }
}

// plain count (fallback path)
__global__ void k_count(const int* __restrict__ col, int* __restrict__ deg) {
    int i = blockIdx.x * blockDim.x + threadIdx.x;
    if (i < NE) atomicAdd(&deg[col[i]], 1);
}

// ---------------- reduce 8 copies -> deg, dinv, per-XCD prefix, block sums ----
__global__ __launch_bounds__(1024) void k_reduce8(const unsigned* __restrict__ deg8,
                                                  int* __restrict__ deg,
                                                  float* __restrict__ dinv,
                                                  unsigned char* __restrict__ pre8,
                                                  int* __restrict__ bsum) {
    __shared__ int red[1024];
    int t = threadIdx.x;
    int c = blockIdx.x * 1024 + t;
    int d = 0;
    if (c < NN) {
        uint4 a = *(const uint4*)&deg8[(size_t)c * 8];
        uint4 b = *(const uint4*)&deg8[(size_t)c * 8 + 4];
        unsigned p0 = 0, p1 = a.x, p2 = p1 + a.y, p3 = p2 + a.z;
        unsigned p4 = p3 + a.w, p5 = p4 + b.x, p6 = p5 + b.y, p7 = p6 + b.z;
        unsigned total = p7 + b.w;
        uint2 packed;
        packed.x = p0 | (p1 << 8) | (p2 << 16) | (p3 << 24);
        packed.y = p4 | (p5 << 8) | (p6 << 16) | (p7 << 24);
        *(uint2*)&pre8[(size_t)c * 8] = packed;
        d = (int)total;
        deg[c] = d;
        dinv[c] = 1.0f / sqrtf((float)(d + 1));
    }
    red[t] = d;
    __syncthreads();
    for (int off = 512; off > 0; off >>= 1) {
        if (t < off) red[t] += red[t + off];
        __syncthreads();
    }
    if (t == 0) bsum[blockIdx.x] = red[0];
}

// fallback: per-block sums + dinv
__global__ __launch_bounds__(1024) void k_blocksum_dinv(const int* __restrict__ deg,
                                                        int* __restrict__ bsum,
                                                        float* __restrict__ dinv) {
    __shared__ int red[1024];
    int t = threadIdx.x;
    int i = blockIdx.x * 1024 + t;
    int d = i < NN ? deg[i] : 0;
    if (i < NN) dinv[i] = 1.0f / sqrtf((float)(d + 1));
    red[t] = d;
    __syncthreads();
    for (int off = 512; off > 0; off >>= 1) {
        if (t < off) red[t] += red[t + off];
        __syncthreads();
    }
    if (t == 0) bsum[blockIdx.x] = red[0];
}

// ---------------- scan: every block redundantly scans bsum, then local scan ----
__global__ __launch_bounds__(1024) void k_scanwrite2(const int* __restrict__ deg,
                                                     const int* __restrict__ bsum,
                                                     int* __restrict__ rowptr) {
    __shared__ int sb[128];
    __shared__ int s[1024];
    int t = threadIdx.x;
    if (t < 128) sb[t] = t < NBLK ? bsum[t] : 0;
    __syncthreads();
    for (int off = 1; off < 128; off <<= 1) {
        int v = 0;
        if (t < 128 && t >= off) v = sb[t - off];
        __syncthreads();
        if (t < 128) sb[t] += v;
        __syncthreads();
    }
    int boff = blockIdx.x == 0 ? 0 : sb[blockIdx.x - 1];
    int i = blockIdx.x * 1024 + t;
    int v = i < NN ? deg[i] : 0;
    s[t] = v;
    __syncthreads();
    for (int off = 1; off < 1024; off <<= 1) {
        int u = t >= off ? s[t - off] : 0;
        __syncthreads();
        s[t] += u;
        __syncthreads();
    }
    if (i < NN) rowptr[i] = boff + s[t] - v;  // exclusive
    if (i == 0) rowptr[NN] = NE;
}

// fallback scan kernels
__global__ void k_scanbsum(const int* __restrict__ bsum, int* __restrict__ boff) {
    __shared__ int s[128];
    int t = threadIdx.x;
    s[t] = t < NBLK ? bsum[t] : 0;
    __syncthreads();
    for (int off = 1; off < 128; off <<= 1) {
        int v = t >= off ? s[t - off] : 0;
        __syncthreads();
        s[t] += v;
        __syncthreads();
    }
    if (t < NBLK) boff[t] = (t == 0) ? 0 : s[t - 1];
}
__global__ __launch_bounds__(1024) void k_scanwrite(const int* __restrict__ deg,
                                                    const int* __restrict__ boff,
                                                    int* __restrict__ rowptr) {
    __shared__ int s[1024];
    int t = threadIdx.x;
    int i = blockIdx.x * 1024 + t;
    int v = i < NN ? deg[i] : 0;
    s[t] = v;
    __syncthreads();
    for (int off = 1; off < 1024; off <<= 1) {
        int u = t >= off ? s[t - off] : 0;
        __syncthreads();
        s[t] += u;
        __syncthreads();
    }
    if (i < NN) rowptr[i] = boff[blockIdx.x] + s[t] - v;
    if (i == 0) rowptr[NN] = NE;
}

// ---------------- fill CSR without atomics (eslot + per-XCD prefix) ----------
__global__ void k_fill8(const int* __restrict__ row, const int* __restrict__ col,
                        const int* __restrict__ rowptr,
                        const unsigned char* __restrict__ pre8,
                        const unsigned* __restrict__ eslot, int* __restrict__ esrc) {
    int i = blockIdx.x * blockDim.x + threadIdx.x;
    if (i < NE) {
        int c = col[i];
        unsigned es = eslot[i];
        int pos = rowptr[c] + (int)pre8[(size_t)c * 8 + (es >> 8)] + (int)(es & 255u);
        esrc[pos] = row[i];
    }
}

// fallback fill with cursor atomics
__global__ void k_fill(const int* __restrict__ row, const int* __restrict__ col,
                       const int* __restrict__ rowptr, int* __restrict__ cnt,
                       int* __restrict__ esrc) {
    int i = blockIdx.x * blockDim.x + threadIdx.x;
    if (i < NE) {
        int c = col[i];
        int pos = rowptr[c] + atomicAdd(&cnt[c], 1);
        esrc[pos] = row[i];
    }
}

// ---------------- W -> pre-swizzled bf16 (global, 32 KB) ----------------
__global__ void k_wb(const float* __restrict__ W, unsigned short* __restrict__ wbs) {
    int unit = blockIdx.x * 256 + threadIdx.x;  // 2048 units x 8 elems
    int row = unit >> 4;                        // output-feature row
    int c0 = (unit & 15) * 8;                   // k offset
    float4 v0 = *(const float4*)(W + row * DD + c0);
    float4 v1 = *(const float4*)(W + row * DD + c0 + 4);
    bf16x8 h;
    h[0] = (short)f2bf(v0.x); h[1] = (short)f2bf(v0.y);
    h[2] = (short)f2bf(v0.z); h[3] = (short)f2bf(v0.w);
    h[4] = (short)f2bf(v1.x); h[5] = (short)f2bf(v1.y);
    h[6] = (short)f2bf(v1.z); h[7] = (short)f2bf(v1.w);
    int byte = (row * 256 + c0 * 2) ^ ((row & 7) << 4);  // XOR-swizzle
    *(bf16x8*)((char*)wbs + byte) = h;
}

// ---------------- MFMA GEMM: yb8[m] = fp8( dinv[m] * (x[m] @ W^T) ), permuted ----
// Byte p of row m holds feature n = (p&7)*16 + (p>>3)  (writer-natural order).
__global__ __launch_bounds__(256) void k_ygemm(const float* __restrict__ x,
                                               const unsigned short* __restrict__ wbs,
                                               const float* __restrict__ dinv,
                                               unsigned char* __restrict__ yb8) {
    __shared__ unsigned short wb[DD * DD];  // 32 KB, already swizzled
    int t = threadIdx.x;
#pragma unroll
    for (int i = 0; i < 8; ++i)
        ((float4*)wb)[t + 256 * i] = ((const float4*)wbs)[t + 256 * i];
    __syncthreads();

    int wave = t >> 6;
    int lane = t & 63;
    int lrow = lane & 15;   // A row within 16-tile / D col (feature n)
    int kg = lane >> 4;     // k-group 0..3

    int arow = blockIdx.x * 64 + wave * 16 + lrow;
    int arc = arow < NN ? arow : NN - 1;  // clamped rows' outputs never written
    bf16x8 afrag[4];
#pragma unroll
    for (int ks = 0; ks < 4; ++ks) {
        const float* src = x + (size_t)arc * DD + ks * 32 + kg * 8;
        float4 v0 = *(const float4*)src;
        float4 v1 = *(const float4*)(src + 4);
        bf16x8 h;
        h[0] = (short)f2bf(v0.x); h[1] = (short)f2bf(v0.y);
        h[2] = (short)f2bf(v0.z); h[3] = (short)f2bf(v0.w);
        h[4] = (short)f2bf(v1.x); h[5] = (short)f2bf(v1.y);
        h[6] = (short)f2bf(v1.z); h[7] = (short)f2bf(v1.w);
        afrag[ks] = h;
    }

    f32x4 acc[8];
#pragma unroll
    for (int ct = 0; ct < 8; ++ct) acc[ct] = (f32x4)(0.f);

#pragma unroll
    for (int ct = 0; ct < 8; ++ct) {
        int wrow = ct * 16 + lrow;  // output-feature index
#pragma unroll
        for (int ks = 0; ks < 4; ++ks) {
            int byte = (wrow * 256 + ks * 64 + kg * 16) ^ ((wrow & 7) << 4);
            bf16x8 bfrag = *(const bf16x8*)((char*)wb + byte);
            acc[ct] = __builtin_amdgcn_mfma_f32_16x16x32_bf16(afrag[ks], bfrag, acc[ct], 0, 0, 0);
        }
    }

    // epilogue: lane owns rows m = base+wave*16+kg*4+j, features n=ct*16+lrow.
    // Pack the 8 ct-values as 8 consecutive fp8 bytes at offset lrow*8.
#pragma unroll
    for (int j = 0; j < 4; ++j) {
        int m = blockIdx.x * 64 + wave * 16 + kg * 4 + j;
        if (m < NN) {
            float s = dinv[m];
            unsigned w0 = 0, w1 = 0;
            w0 = __builtin_amdgcn_cvt_pk_fp8_f32(s * acc[0][j], s * acc[1][j], w0, false);
            w0 = __builtin_amdgcn_cvt_pk_fp8_f32(s * acc[2][j], s * acc[3][j], w0, true);
            w1 = __builtin_amdgcn_cvt_pk_fp8_f32(s * acc[4][j], s * acc[5][j], w1, false);
            w1 = __builtin_amdgcn_cvt_pk_fp8_f32(s * acc[6][j], s * acc[7][j], w1, true);
            uint2 o; o.x = w0; o.y = w1;
            *(uint2*)(yb8 + (size_t)m * DD + lrow * 8) = o;
        }
    }
}

// ---------------- fused gather (fp8) + epilogue ----------------
__global__ __launch_bounds__(256) void k_gather_fp8(const int* __restrict__ rowptr,
                                                    const int* __restrict__ esrc,
                                                    const unsigned char* __restrict__ yb8,
                                                    const float* __restrict__ x,
                                                    const float* __restrict__ dinv,
                                                    const float* __restrict__ bias,
                                                    float* __restrict__ out) {
    int t = threadIdx.x;
    int gl = t & 31;
    int node = blockIdx.x * 8 + (t >> 5);
    if (node >= NN) return;
    int beg = rowptr[node];
    int end = rowptr[node + 1];
    float dc = dinv[node];

    // self term
    unsigned su = *(const unsigned*)(yb8 + (size_t)node * DD + gl * 4);
    f32x2 a01 = __builtin_amdgcn_cvt_pk_f32_fp8(su, false);
    f32x2 a23 = __builtin_amdgcn_cvt_pk_f32_fp8(su, true);

    int e = beg;
    for (; e + 7 < end; e += 8) {
        unsigned uu[8];
#pragma unroll
        for (int u = 0; u < 8; ++u) {
            int r = esrc[e + u];
            uu[u] = *(const unsigned*)(yb8 + (size_t)r * DD + gl * 4);
        }
#pragma unroll
        for (int u = 0; u < 8; ++u) {
            a01 += __builtin_amdgcn_cvt_pk_f32_fp8(uu[u], false);
            a23 += __builtin_amdgcn_cvt_pk_f32_fp8(uu[u], true);
        }
    }
    for (; e < end; ++e) {
        int r = esrc[e];
        unsigned u = *(const unsigned*)(yb8 + (size_t)r * DD + gl * 4);
        a01 += __builtin_amdgcn_cvt_pk_f32_fp8(u, false);
        a23 += __builtin_amdgcn_cvt_pk_f32_fp8(u, true);
    }

    float vals[4] = {a01.x, a01.y, a23.x, a23.y};
    int q = gl >> 1;          // p>>3 for all 4 positions
    int c0 = (gl & 1) * 4;    // (p&7) base
#pragma unroll
    for (int i = 0; i < 4; ++i) {
        int n = (c0 + i) * 16 + q;
        float h = dc * vals[i] + bias[n];
        out[(size_t)node * DD + n] = x[(size_t)node * DD + n] + fmaxf(h, 0.f);
    }
}

// ---------------- f32 fallback gather ----------------
__global__ __launch_bounds__(256) void k_gather(const int* __restrict__ rowptr,
                                                const int* __restrict__ esrc,
                                                const float* __restrict__ x,
                                                const float* __restrict__ dinv,
                                                float* __restrict__ agg) {
    int t = threadIdx.x;
    int lane = t & 31;
    int node = blockIdx.x * 8 + (t >> 5);
    if (node >= NN) return;
    int beg = rowptr[node];
    int end = rowptr[node + 1];
    float dc = dinv[node];
    float4 xv = ((const float4*)(x + (size_t)node * DD))[lane];
    float4 acc;
    acc.x = dc * xv.x; acc.y = dc * xv.y; acc.z = dc * xv.z; acc.w = dc * xv.w;
    int e = beg;
    for (; e + 1 < end; e += 2) {
        int r0 = esrc[e];
        int r1 = esrc[e + 1];
        float s0 = dinv[r0];
        float s1 = dinv[r1];
        float4 v0 = ((const float4*)(x + (size_t)r0 * DD))[lane];
        float4 v1 = ((const float4*)(x + (size_t)r1 * DD))[lane];
        acc.x += s0 * v0.x + s1 * v1.x;
        acc.y += s0 * v0.y + s1 * v1.y;
        acc.z += s0 * v0.z + s1 * v1.z;
        acc.w += s0 * v0.w + s1 * v1.w;
    }
    if (e < end) {
        int r = esrc[e];
        float s = dinv[r];
        float4 v = ((const float4*)(x + (size_t)r * DD))[lane];
        acc.x += s * v.x; acc.y += s * v.y; acc.z += s * v.z; acc.w += s * v.w;
    }
    acc.x *= dc; acc.y *= dc; acc.z *= dc; acc.w *= dc;
    ((float4*)(agg + (size_t)node * DD))[lane] = acc;
}

// ---------------- fallback W -> Wt ----------------
__global__ void k_transpose_w(const float* __restrict__ W, float* __restrict__ Wt) {
    int c = blockIdx.x;
    int k = threadIdx.x;
    Wt[k * DD + c] = W[c * DD + k];
}

// ---------------- fallback vector GEMM ----------------
__global__ __launch_bounds__(256) void k_gemm(const float* __restrict__ x,
                                              const float* __restrict__ Wt,
                                              const float* __restrict__ bias,
                                              float* __restrict__ out) {
    __shared__ float wt[DD * DD];
    int t = threadIdx.x;
    for (int i = t; i < DD * DD / 4; i += 256)
        ((float4*)wt)[i] = ((const float4*)Wt)[i];
    __syncthreads();

    int grp = t >> 5;
    int c4  = (t & 31) * 4;
    int rbase = blockIdx.x * 64 + grp * 8;

    float acc[8][4];
#pragma unroll
    for (int i = 0; i < 8; i++)
#pragma unroll
        for (int j = 0; j < 4; j++) acc[i][j] = 0.0f;

    for (int k = 0; k < DD; k += 4) {
        float4 w0 = *(const float4*)&wt[(k + 0) * DD + c4];
        float4 w1 = *(const float4*)&wt[(k + 1) * DD + c4];
        float4 w2 = *(const float4*)&wt[(k + 2) * DD + c4];
        float4 w3 = *(const float4*)&wt[(k + 3) * DD + c4];
#pragma unroll
        for (int i = 0; i < 8; i++) {
            int rr = rbase + i;
            rr = rr < NN ? rr : NN - 1;
            float4 a = *(const float4*)&out[(size_t)rr * DD + k];
            acc[i][0] += a.x * w0.x + a.y * w1.x + a.z * w2.x + a.w * w3.x;
            acc[i][1] += a.x * w0.y + a.y * w1.y + a.z * w2.y + a.w * w3.y;
            acc[i][2] += a.x * w0.z + a.y * w1.z + a.z * w2.z + a.w * w3.z;
            acc[i][3] += a.x * w0.w + a.y * w1.w + a.z * w2.w + a.w * w3.w;
        }
    }

    float4 bv = *(const float4*)&bias[c4];
#pragma unroll
    for (int i = 0; i < 8; i++) {
        int r = rbase + i;
        if (r < NN) {
            float4 xv = *(const float4*)&x[(size_t)r * DD + c4];
            float4 o;
            o.x = xv.x + fmaxf(acc[i][0] + bv.x, 0.0f);
            o.y = xv.y + fmaxf(acc[i][1] + bv.y, 0.0f);
            o.z = xv.z + fmaxf(acc[i][2] + bv.z, 0.0f);
            o.w = xv.w + fmaxf(acc[i][3] + bv.w, 0.0f);
            *(float4*)&out[(size_t)r * DD + c4] = o;
        }
    }
}

extern "C" void kernel_launch(void* const* d_in, const int* in_sizes, int n_in,
                              void* d_out, int out_size, void* d_ws, size_t ws_size,
                              hipStream_t stream) {
    const float* x   = (const float*)d_in[0];
    const int*   ei  = (const int*)d_in[1];
    const float* W   = (const float*)d_in[2];
    const float* b   = (const float*)d_in[3];
    const int* row = ei;        // edge_index[0] = source
    const int* col = ei + NE;   // edge_index[1] = target

    float* out = (float*)d_out;

    // workspace layout (bytes), all 16-B aligned:
    //   deg8   : [0,          3200000)   u32[NN*8]
    //   deg    : [3200000,    3600000)
    //   dinv   : [3600000,    4000000)
    //   rowptr : [4000000,    4400016)
    //   bsum   : [4400016,    4400416)
    //   pre8   : [4400416,    5200416)   u8[NN*8]
    //   wbs    : [5200416,    5265952)
    //   esrc   : [5265952,   11665952)
    //   eslot  : [11665952,  18065952)
    //   yb8    : [18065952,  30865952)
    char* ws = (char*)d_ws;
    unsigned* deg8  = (unsigned*)ws;
    int*   deg    = (int*)(ws + 3200000);
    float* dinv   = (float*)(ws + 3600000);
    int*   rowptr = (int*)(ws + 4000000);
    int*   bsum   = (int*)(ws + 4400016);
    unsigned char* pre8 = (unsigned char*)(ws + 4400416);
    unsigned short* wbs = (unsigned short*)(ws + 5200416);
    float* Wt     = (float*)(ws + 5200416);
    int*   esrc   = (int*)(ws + 5265952);
    unsigned* eslot = (unsigned*)(ws + 11665952);
    unsigned char* yb8 = (unsigned char*)(ws + 18065952);

    bool big_ws = ws_size >= 30900000;

    if (big_ws) {
        hipMemsetAsync(deg8, 0, (size_t)NN * 8 * sizeof(unsigned), stream);
        k_count8<<<(NE + 255) / 256, 256, 0, stream>>>(col, deg8, eslot);
        k_reduce8<<<NBLK, 1024, 0, stream>>>(deg8, deg, dinv, pre8, bsum);
        k_scanwrite2<<<NBLK, 1024, 0, stream>>>(deg, bsum, rowptr);
        k_wb<<<8, 256, 0, stream>>>(W, wbs);
        k_ygemm<<<(NN + 63) / 64, 256, 0, stream>>>(x, wbs, dinv, yb8);
        k_fill8<<<(NE + 255) / 256, 256, 0, stream>>>(row, col, rowptr, pre8, eslot, esrc);
        k_gather_fp8<<<(NN + 7) / 8, 256, 0, stream>>>(rowptr, esrc, yb8, x, dinv, b, out);
    } else {
        int* cnt = (int*)ws;  // reuse deg8 region as count/cursor
        hipMemsetAsync(cnt, 0, NN * sizeof(int), stream);
        k_count<<<(NE + 255) / 256, 256, 0, stream>>>(col, cnt);
        k_blocksum_dinv<<<NBLK, 1024, 0, stream>>>(cnt, bsum, dinv);
        k_scanbsum<<<1, 128, 0, stream>>>(bsum, (int*)(ws + 4400416));
        k_scanwrite<<<NBLK, 1024, 0, stream>>>(cnt, (int*)(ws + 4400416), rowptr);
        hipMemsetAsync(cnt, 0, NN * sizeof(int), stream);
        k_fill<<<(NE + 255) / 256, 256, 0, stream>>>(row, col, rowptr, cnt, esrc);
        k_gather<<<(NN + 7) / 8, 256, 0, stream>>>(rowptr, esrc, x, dinv, out);
        k_transpose_w<<<DD, DD, 0, stream>>>(W, Wt);
        k_gemm<<<(NN + 63) / 64, 256, 0, stream>>>(x, Wt, b, out);
    }
}

// Round 10
// 135.037 us; speedup vs baseline: 1.3956x; 1.3956x over previous
//
#include <hip/hip_runtime.h>

#define NN 100000
#define NE 1600000
#define DD 128
#define NBLK 98    // ceil(NN / 1024) (fallback scan)
#define NBUK 782   // ceil(NN / 128) buckets of 128 nodes
#define NB_AC 256  // blocks in hist/scatter passes
#define CHUNK 6250 // NE / NB_AC exactly
#define SCAN_N (NBUK * NB_AC)  // 200192
#define NB_SCAN 196            // ceil(SCAN_N / 1024)

typedef __attribute__((ext_vector_type(8))) short bf16x8;
typedef __attribute__((ext_vector_type(4))) float f32x4;
typedef __attribute__((ext_vector_type(2))) float f32x2;

__device__ __forceinline__ float bf2f(unsigned short u) {
    return __uint_as_float(((unsigned)u) << 16);
}
__device__ __forceinline__ unsigned short f2bf(float f) {
    unsigned u = __float_as_uint(f);
    u += 0x7FFFu + ((u >> 16) & 1u);  // round to nearest even
    return (unsigned short)(u >> 16);
}

// ---------------- A: per-block bucket histogram (LDS atomics only) ----------
__global__ __launch_bounds__(256) void k_hist(const int* __restrict__ col,
                                              unsigned* __restrict__ part) {
    __shared__ unsigned hist[NBUK];
    int t = threadIdx.x, blk = blockIdx.x;
    for (int i = t; i < NBUK; i += 256) hist[i] = 0;
    __syncthreads();
    int beg = blk * CHUNK, end = beg + CHUNK;
    for (int e = beg + t; e < end; e += 256)
        atomicAdd(&hist[col[e] >> 7], 1u);
    __syncthreads();
    for (int i = t; i < NBUK; i += 256)
        part[(size_t)i * NB_AC + blk] = hist[i];  // bucket-major layout
}

// ---------------- B1: block sums of part (scan order) ----------------
__global__ __launch_bounds__(1024) void k_bsum(const unsigned* __restrict__ part,
                                               unsigned* __restrict__ sb) {
    __shared__ unsigned red[1024];
    int t = threadIdx.x;
    int i = blockIdx.x * 1024 + t;
    red[t] = i < SCAN_N ? part[i] : 0;
    __syncthreads();
    for (int off = 512; off > 0; off >>= 1) {
        if (t < off) red[t] += red[t + off];
        __syncthreads();
    }
    if (t == 0) sb[blockIdx.x] = red[0];
}

// ---------------- B2: exclusive scan part -> off ----------------
__global__ __launch_bounds__(1024) void k_scanpart(const unsigned* __restrict__ part,
                                                   const unsigned* __restrict__ sb,
                                                   unsigned* __restrict__ off) {
    __shared__ unsigned s2[256];
    __shared__ unsigned s[1024];
    int t = threadIdx.x;
    if (t < 256) s2[t] = (t < NB_SCAN) ? sb[t] : 0;
    __syncthreads();
    for (int o = 1; o < 256; o <<= 1) {
        unsigned v = 0;
        if (t < 256 && t >= o) v = s2[t - o];
        __syncthreads();
        if (t < 256) s2[t] += v;
        __syncthreads();
    }
    unsigned boff = blockIdx.x == 0 ? 0 : s2[blockIdx.x - 1];
    int i = blockIdx.x * 1024 + t;
    unsigned v = i < SCAN_N ? part[i] : 0;
    s[t] = v;
    __syncthreads();
    for (int o = 1; o < 1024; o <<= 1) {
        unsigned u = t >= o ? s[t - o] : 0;
        __syncthreads();
        s[t] += u;
        __syncthreads();
    }
    if (i < SCAN_N) off[i] = boff + s[t] - v;  // exclusive prefix
}

// ---------------- C: scatter packed edges into bucket-contiguous array -------
// MUST use the same (block -> edge chunk) mapping as k_hist.
__global__ __launch_bounds__(256) void k_scatter_pk(const int* __restrict__ row,
                                                    const int* __restrict__ col,
                                                    const unsigned* __restrict__ off,
                                                    unsigned* __restrict__ packed) {
    __shared__ unsigned cur[NBUK];
    int t = threadIdx.x, blk = blockIdx.x;
    for (int i = t; i < NBUK; i += 256) cur[i] = off[(size_t)i * NB_AC + blk];
    __syncthreads();
    int beg = blk * CHUNK, end = beg + CHUNK;
    for (int e = beg + t; e < end; e += 256) {
        int c = col[e];
        unsigned pos = atomicAdd(&cur[c >> 7], 1u);  // LDS cursor
        packed[pos] = ((unsigned)(c & 127) << 17) | (unsigned)row[e];
    }
}

// ---------------- D: per-bucket CSR finalize: deg/dinv/rowptr/esrc ----------
__global__ __launch_bounds__(256) void k_bucket_csr(const unsigned* __restrict__ off,
                                                    const unsigned* __restrict__ packed,
                                                    float* __restrict__ dinv,
                                                    int* __restrict__ rowptr,
                                                    int* __restrict__ esrc) {
    __shared__ unsigned deg[128], pre[128], tmp[128];
    int t = threadIdx.x;
    int buk = blockIdx.x;
    unsigned bstart = off[(size_t)buk * NB_AC];
    unsigned bend = (buk == NBUK - 1) ? (unsigned)NE : off[(size_t)(buk + 1) * NB_AC];
    if (t < 128) deg[t] = 0;
    __syncthreads();
    for (unsigned e = bstart + t; e < bend; e += 256)
        atomicAdd(&deg[packed[e] >> 17], 1u);
    __syncthreads();
    if (t < 128) tmp[t] = deg[t];
    __syncthreads();
    for (int o = 1; o < 128; o <<= 1) {
        unsigned v = 0;
        if (t < 128 && t >= o) v = tmp[t - o];
        __syncthreads();
        if (t < 128) tmp[t] += v;
        __syncthreads();
    }
    if (t < 128) {
        pre[t] = tmp[t] - deg[t];  // exclusive
        int n = buk * 128 + t;
        if (n < NN) {
            dinv[n] = 1.0f / sqrtf((float)(deg[t] + 1));
            rowptr[n] = (int)(bstart + pre[t]);
        }
    }
    if (buk == NBUK - 1 && t == 0) rowptr[NN] = NE;
    __syncthreads();
    if (t < 128) deg[t] = pre[t];  // reuse as cursor
    __syncthreads();
    for (unsigned e = bstart + t; e < bend; e += 256) {
        unsigned p = packed[e];
        unsigned pos = atomicAdd(&deg[p >> 17], 1u);
        esrc[bstart + pos] = (int)(p & 0x1FFFFu);
    }
}

// ---------------- W -> pre-swizzled bf16 (global, 32 KB) ----------------
__global__ void k_wb(const float* __restrict__ W, unsigned short* __restrict__ wbs) {
    int unit = blockIdx.x * 256 + threadIdx.x;  // 2048 units x 8 elems
    int row = unit >> 4;                        // output-feature row
    int c0 = (unit & 15) * 8;                   // k offset
    float4 v0 = *(const float4*)(W + row * DD + c0);
    float4 v1 = *(const float4*)(W + row * DD + c0 + 4);
    bf16x8 h;
    h[0] = (short)f2bf(v0.x); h[1] = (short)f2bf(v0.y);
    h[2] = (short)f2bf(v0.z); h[3] = (short)f2bf(v0.w);
    h[4] = (short)f2bf(v1.x); h[5] = (short)f2bf(v1.y);
    h[6] = (short)f2bf(v1.z); h[7] = (short)f2bf(v1.w);
    int byte = (row * 256 + c0 * 2) ^ ((row & 7) << 4);  // XOR-swizzle
    *(bf16x8*)((char*)wbs + byte) = h;
}

// ---------------- MFMA GEMM: yb8[m] = fp8( dinv[m] * (x[m] @ W^T) ), permuted ----
// Byte p of row m holds feature n = (p&7)*16 + (p>>3)  (writer-natural order).
__global__ __launch_bounds__(256) void k_ygemm(const float* __restrict__ x,
                                               const unsigned short* __restrict__ wbs,
                                               const float* __restrict__ dinv,
                                               unsigned char* __restrict__ yb8) {
    __shared__ unsigned short wb[DD * DD];  // 32 KB, already swizzled
    int t = threadIdx.x;
#pragma unroll
    for (int i = 0; i < 8; ++i)
        ((float4*)wb)[t + 256 * i] = ((const float4*)wbs)[t + 256 * i];
    __syncthreads();

    int wave = t >> 6;
    int lane = t & 63;
    int lrow = lane & 15;   // A row within 16-tile / D col (feature n)
    int kg = lane >> 4;     // k-group 0..3

    int arow = blockIdx.x * 64 + wave * 16 + lrow;
    int arc = arow < NN ? arow : NN - 1;  // clamped rows' outputs never written
    bf16x8 afrag[4];
#pragma unroll
    for (int ks = 0; ks < 4; ++ks) {
        const float* src = x + (size_t)arc * DD + ks * 32 + kg * 8;
        float4 v0 = *(const float4*)src;
        float4 v1 = *(const float4*)(src + 4);
        bf16x8 h;
        h[0] = (short)f2bf(v0.x); h[1] = (short)f2bf(v0.y);
        h[2] = (short)f2bf(v0.z); h[3] = (short)f2bf(v0.w);
        h[4] = (short)f2bf(v1.x); h[5] = (short)f2bf(v1.y);
        h[6] = (short)f2bf(v1.z); h[7] = (short)f2bf(v1.w);
        afrag[ks] = h;
    }

    f32x4 acc[8];
#pragma unroll
    for (int ct = 0; ct < 8; ++ct) acc[ct] = (f32x4)(0.f);

#pragma unroll
    for (int ct = 0; ct < 8; ++ct) {
        int wrow = ct * 16 + lrow;  // output-feature index
#pragma unroll
        for (int ks = 0; ks < 4; ++ks) {
            int byte = (wrow * 256 + ks * 64 + kg * 16) ^ ((wrow & 7) << 4);
            bf16x8 bfrag = *(const bf16x8*)((char*)wb + byte);
            acc[ct] = __builtin_amdgcn_mfma_f32_16x16x32_bf16(afrag[ks], bfrag, acc[ct], 0, 0, 0);
        }
    }

    // epilogue: pack 8 ct-values as 8 consecutive fp8 bytes at offset lrow*8.
#pragma unroll
    for (int j = 0; j < 4; ++j) {
        int m = blockIdx.x * 64 + wave * 16 + kg * 4 + j;
        if (m < NN) {
            float s = dinv[m];
            unsigned w0 = 0, w1 = 0;
            w0 = __builtin_amdgcn_cvt_pk_fp8_f32(s * acc[0][j], s * acc[1][j], w0, false);
            w0 = __builtin_amdgcn_cvt_pk_fp8_f32(s * acc[2][j], s * acc[3][j], w0, true);
            w1 = __builtin_amdgcn_cvt_pk_fp8_f32(s * acc[4][j], s * acc[5][j], w1, false);
            w1 = __builtin_amdgcn_cvt_pk_fp8_f32(s * acc[6][j], s * acc[7][j], w1, true);
            uint2 o; o.x = w0; o.y = w1;
            *(uint2*)(yb8 + (size_t)m * DD + lrow * 8) = o;
        }
    }
}

// ---------------- fused gather (fp8) + epilogue ----------------
__global__ __launch_bounds__(256) void k_gather_fp8(const int* __restrict__ rowptr,
                                                    const int* __restrict__ esrc,
                                                    const unsigned char* __restrict__ yb8,
                                                    const float* __restrict__ x,
                                                    const float* __restrict__ dinv,
                                                    const float* __restrict__ bias,
                                                    float* __restrict__ out) {
    int t = threadIdx.x;
    int gl = t & 31;
    int node = blockIdx.x * 8 + (t >> 5);
    if (node >= NN) return;
    int beg = rowptr[node];
    int end = rowptr[node + 1];
    float dc = dinv[node];

    // self term
    unsigned su = *(const unsigned*)(yb8 + (size_t)node * DD + gl * 4);
    f32x2 a01 = __builtin_amdgcn_cvt_pk_f32_fp8(su, false);
    f32x2 a23 = __builtin_amdgcn_cvt_pk_f32_fp8(su, true);

    int e = beg;
    for (; e + 7 < end; e += 8) {
        unsigned uu[8];
#pragma unroll
        for (int u = 0; u < 8; ++u) {
            int r = esrc[e + u];
            uu[u] = *(const unsigned*)(yb8 + (size_t)r * DD + gl * 4);
        }
#pragma unroll
        for (int u = 0; u < 8; ++u) {
            a01 += __builtin_amdgcn_cvt_pk_f32_fp8(uu[u], false);
            a23 += __builtin_amdgcn_cvt_pk_f32_fp8(uu[u], true);
        }
    }
    for (; e < end; ++e) {
        int r = esrc[e];
        unsigned u = *(const unsigned*)(yb8 + (size_t)r * DD + gl * 4);
        a01 += __builtin_amdgcn_cvt_pk_f32_fp8(u, false);
        a23 += __builtin_amdgcn_cvt_pk_f32_fp8(u, true);
    }

    float vals[4] = {a01.x, a01.y, a23.x, a23.y};
    int q = gl >> 1;          // p>>3 for all 4 positions
    int c0 = (gl & 1) * 4;    // (p&7) base
#pragma unroll
    for (int i = 0; i < 4; ++i) {
        int n = (c0 + i) * 16 + q;
        float h = dc * vals[i] + bias[n];
        out[(size_t)node * DD + n] = x[(size_t)node * DD + n] + fmaxf(h, 0.f);
    }
}

// ================= fallback path (small ws) =================
__global__ void k_count(const int* __restrict__ col, int* __restrict__ deg) {
    int i = blockIdx.x * blockDim.x + threadIdx.x;
    if (i < NE) atomicAdd(&deg[col[i]], 1);
}
__global__ __launch_bounds__(1024) void k_blocksum_dinv(const int* __restrict__ deg,
                                                        int* __restrict__ bsum,
                                                        float* __restrict__ dinv) {
    __shared__ int red[1024];
    int t = threadIdx.x;
    int i = blockIdx.x * 1024 + t;
    int d = i < NN ? deg[i] : 0;
    if (i < NN) dinv[i] = 1.0f / sqrtf((float)(d + 1));
    red[t] = d;
    __syncthreads();
    for (int off = 512; off > 0; off >>= 1) {
        if (t < off) red[t] += red[t + off];
        __syncthreads();
    }
    if (t == 0) bsum[blockIdx.x] = red[0];
}
__global__ void k_scanbsum(const int* __restrict__ bsum, int* __restrict__ boff) {
    __shared__ int s[128];
    int t = threadIdx.x;
    s[t] = t < NBLK ? bsum[t] : 0;
    __syncthreads();
    for (int off = 1; off < 128; off <<= 1) {
        int v = t >= off ? s[t - off] : 0;
        __syncthreads();
        s[t] += v;
        __syncthreads();
    }
    if (t < NBLK) boff[t] = (t == 0) ? 0 : s[t - 1];
}
__global__ __launch_bounds__(1024) void k_scanwrite(const int* __restrict__ deg,
                                                    const int* __restrict__ boff,
                                                    int* __restrict__ rowptr) {
    __shared__ int s[1024];
    int t = threadIdx.x;
    int i = blockIdx.x * 1024 + t;
    int v = i < NN ? deg[i] : 0;
    s[t] = v;
    __syncthreads();
    for (int off = 1; off < 1024; off <<= 1) {
        int u = t >= off ? s[t - off] : 0;
        __syncthreads();
        s[t] += u;
        __syncthreads();
    }
    if (i < NN) rowptr[i] = boff[blockIdx.x] + s[t] - v;
    if (i == 0) rowptr[NN] = NE;
}
__global__ void k_fill(const int* __restrict__ row, const int* __restrict__ col,
                       const int* __restrict__ rowptr, int* __restrict__ cnt,
                       int* __restrict__ esrc) {
    int i = blockIdx.x * blockDim.x + threadIdx.x;
    if (i < NE) {
        int c = col[i];
        int pos = rowptr[c] + atomicAdd(&cnt[c], 1);
        esrc[pos] = row[i];
    }
}
__global__ __launch_bounds__(256) void k_gather(const int* __restrict__ rowptr,
                                                const int* __restrict__ esrc,
                                                const float* __restrict__ x,
                                                const float* __restrict__ dinv,
                                                float* __restrict__ agg) {
    int t = threadIdx.x;
    int lane = t & 31;
    int node = blockIdx.x * 8 + (t >> 5);
    if (node >= NN) return;
    int beg = rowptr[node];
    int end = rowptr[node + 1];
    float dc = dinv[node];
    float4 xv = ((const float4*)(x + (size_t)node * DD))[lane];
    float4 acc;
    acc.x = dc * xv.x; acc.y = dc * xv.y; acc.z = dc * xv.z; acc.w = dc * xv.w;
    int e = beg;
    for (; e + 1 < end; e += 2) {
        int r0 = esrc[e];
        int r1 = esrc[e + 1];
        float s0 = dinv[r0];
        float s1 = dinv[r1];
        float4 v0 = ((const float4*)(x + (size_t)r0 * DD))[lane];
        float4 v1 = ((const float4*)(x + (size_t)r1 * DD))[lane];
        acc.x += s0 * v0.x + s1 * v1.x;
        acc.y += s0 * v0.y + s1 * v1.y;
        acc.z += s0 * v0.z + s1 * v1.z;
        acc.w += s0 * v0.w + s1 * v1.w;
    }
    if (e < end) {
        int r = esrc[e];
        float s = dinv[r];
        float4 v = ((const float4*)(x + (size_t)r * DD))[lane];
        acc.x += s * v.x; acc.y += s * v.y; acc.z += s * v.z; acc.w += s * v.w;
    }
    acc.x *= dc; acc.y *= dc; acc.z *= dc; acc.w *= dc;
    ((float4*)(agg + (size_t)node * DD))[lane] = acc;
}
__global__ void k_transpose_w(const float* __restrict__ W, float* __restrict__ Wt) {
    int c = blockIdx.x;
    int k = threadIdx.x;
    Wt[k * DD + c] = W[c * DD + k];
}
__global__ __launch_bounds__(256) void k_gemm(const float* __restrict__ x,
                                              const float* __restrict__ Wt,
                                              const float* __restrict__ bias,
                                              float* __restrict__ out) {
    __shared__ float wt[DD * DD];
    int t = threadIdx.x;
    for (int i = t; i < DD * DD / 4; i += 256)
        ((float4*)wt)[i] = ((const float4*)Wt)[i];
    __syncthreads();

    int grp = t >> 5;
    int c4  = (t & 31) * 4;
    int rbase = blockIdx.x * 64 + grp * 8;

    float acc[8][4];
#pragma unroll
    for (int i = 0; i < 8; i++)
#pragma unroll
        for (int j = 0; j < 4; j++) acc[i][j] = 0.0f;

    for (int k = 0; k < DD; k += 4) {
        float4 w0 = *(const float4*)&wt[(k + 0) * DD + c4];
        float4 w1 = *(const float4*)&wt[(k + 1) * DD + c4];
        float4 w2 = *(const float4*)&wt[(k + 2) * DD + c4];
        float4 w3 = *(const float4*)&wt[(k + 3) * DD + c4];
#pragma unroll
        for (int i = 0; i < 8; i++) {
            int rr = rbase + i;
            rr = rr < NN ? rr : NN - 1;
            float4 a = *(const float4*)&out[(size_t)rr * DD + k];
            acc[i][0] += a.x * w0.x + a.y * w1.x + a.z * w2.x + a.w * w3.x;
            acc[i][1] += a.x * w0.y + a.y * w1.y + a.z * w2.y + a.w * w3.y;
            acc[i][2] += a.x * w0.z + a.y * w1.z + a.z * w2.z + a.w * w3.z;
            acc[i][3] += a.x * w0.w + a.y * w1.w + a.z * w2.w + a.w * w3.w;
        }
    }

    float4 bv = *(const float4*)&bias[c4];
#pragma unroll
    for (int i = 0; i < 8; i++) {
        int r = rbase + i;
        if (r < NN) {
            float4 xv = *(const float4*)&x[(size_t)r * DD + c4];
            float4 o;
            o.x = xv.x + fmaxf(acc[i][0] + bv.x, 0.0f);
            o.y = xv.y + fmaxf(acc[i][1] + bv.y, 0.0f);
            o.z = xv.z + fmaxf(acc[i][2] + bv.z, 0.0f);
            o.w = xv.w + fmaxf(acc[i][3] + bv.w, 0.0f);
            *(float4*)&out[(size_t)r * DD + c4] = o;
        }
    }
}

extern "C" void kernel_launch(void* const* d_in, const int* in_sizes, int n_in,
                              void* d_out, int out_size, void* d_ws, size_t ws_size,
                              hipStream_t stream) {
    const float* x   = (const float*)d_in[0];
    const int*   ei  = (const int*)d_in[1];
    const float* W   = (const float*)d_in[2];
    const float* b   = (const float*)d_in[3];
    const int* row = ei;        // edge_index[0] = source
    const int* col = ei + NE;   // edge_index[1] = target

    float* out = (float*)d_out;

    // workspace layout (bytes), 16-B aligned:
    //   part   : [0,         800768)   u32[SCAN_N]
    //   off    : [800768,   1601536)   u32[SCAN_N]
    //   sb     : [1601536,  1602352)   u32[196] (+pad)
    //   dinv   : [1602352,  2002352)
    //   rowptr : [2002352,  2402356) -> region to 2402368
    //   packed : [2402368,  8802368)   u32[NE]
    //   wbs    : [8802368,  8867904)
    //   esrc   : [8867904, 15267904)
    //   yb8    : [15267904, 28067904)
    char* ws = (char*)d_ws;
    unsigned* part   = (unsigned*)ws;
    unsigned* off    = (unsigned*)(ws + 800768);
    unsigned* sb     = (unsigned*)(ws + 1601536);
    float*    dinv   = (float*)(ws + 1602352);
    int*      rowptr = (int*)(ws + 2002352);
    unsigned* packed = (unsigned*)(ws + 2402368);
    unsigned short* wbs = (unsigned short*)(ws + 8802368);
    float*    Wt     = (float*)(ws + 8802368);
    int*      esrc   = (int*)(ws + 8867904);
    unsigned char* yb8 = (unsigned char*)(ws + 15267904);

    bool big_ws = ws_size >= 28100000;

    if (big_ws) {
        k_hist<<<NB_AC, 256, 0, stream>>>(col, part);
        k_bsum<<<NB_SCAN, 1024, 0, stream>>>(part, sb);
        k_scanpart<<<NB_SCAN, 1024, 0, stream>>>(part, sb, off);
        k_scatter_pk<<<NB_AC, 256, 0, stream>>>(row, col, off, packed);
        k_bucket_csr<<<NBUK, 256, 0, stream>>>(off, packed, dinv, rowptr, esrc);
        k_wb<<<8, 256, 0, stream>>>(W, wbs);
        k_ygemm<<<(NN + 63) / 64, 256, 0, stream>>>(x, wbs, dinv, yb8);
        k_gather_fp8<<<(NN + 7) / 8, 256, 0, stream>>>(rowptr, esrc, yb8, x, dinv, b, out);
    } else {
        int* cnt  = (int*)ws;                 // reuse part region
        int* bsum = (int*)(ws + 1601536);     // 98 ints fit in sb region
        int* boff = (int*)(ws + 400000);      // inside part region, after cnt
        hipMemsetAsync(cnt, 0, NN * sizeof(int), stream);
        k_count<<<(NE + 255) / 256, 256, 0, stream>>>(col, cnt);
        k_blocksum_dinv<<<NBLK, 1024, 0, stream>>>(cnt, bsum, dinv);
        k_scanbsum<<<1, 128, 0, stream>>>(bsum, boff);
        k_scanwrite<<<NBLK, 1024, 0, stream>>>(cnt, boff, rowptr);
        hipMemsetAsync(cnt, 0, NN * sizeof(int), stream);
        k_fill<<<(NE + 255) / 256, 256, 0, stream>>>(row, col, rowptr, cnt, esrc);
        k_gather<<<(NN + 7) / 8, 256, 0, stream>>>(rowptr, esrc, x, dinv, out);
        k_transpose_w<<<DD, DD, 0, stream>>>(W, Wt);
        k_gemm<<<(NN + 63) / 64, 256, 0, stream>>>(x, Wt, b, out);
    }
}